// Round 6
// baseline (849.718 us; speedup 1.0000x reference)
//
#include <hip/hip_runtime.h>

#define F 32
#define BN_EPS 1e-5f
#define SCAN_CHUNK 2048
#define BSH 10
#define BDST (1 << BSH)   // dsts per bucket (R6: 1024, was 2048)
#define TILEE 2048        // edges per partition block (R6: was 8192; occupancy)

// fp16 storage type for y-side intermediates (accumulate always fp32).
typedef _Float16 h16;
typedef __attribute__((ext_vector_type(4))) _Float16 h16x4;
typedef __attribute__((ext_vector_type(8))) _Float16 h16x8;
typedef __attribute__((ext_vector_type(4))) float f32x4;

__device__ inline float4 load4(const float* p) { return *(const float4*)p; }
__device__ inline float4 load4(const h16* p) {
    h16x4 h = *(const h16x4*)p;
    return make_float4((float)h.x, (float)h.y, (float)h.z, (float)h.w);
}
__device__ inline void store4(float* p, float4 v) { *(float4*)p = v; }
__device__ inline void store4(h16* p, float4 v) {
    h16x4 h;
    h.x = (h16)v.x; h.y = (h16)v.y; h.z = (h16)v.z; h.w = (h16)v.w;
    *(h16x4*)p = h;
}

// ---------------- weight prep ----------------
// WintX: [k][f][3] padded to 4 for the main-linear float4 LDS path (x side).
// WlX:   Wl[i*1024 + k*32 + f] = w_i[f][k] (accum_linear layout, x side).
// Why:   fp16 MFMA B-fragments for the y-side mega-GEMM:
//        Why[(m2h)*512 + l*8 + j] = Wm[h*16+(l&15)][(l>>4)*8+j], m2h=m*2+h.
//        Matrix order m: 0=gamma_y 1=gamma_deg 2=gamma_x 3..5=gamma_list.
__global__ void prep_k(const float* __restrict__ th_mw, const float* __restrict__ th_mb,
                       const float* __restrict__ th_lw, const float* __restrict__ th_lb,
                       const float* __restrict__ ga_mw, const float* __restrict__ ga_mb,
                       const float* __restrict__ ga_lw, const float* __restrict__ ga_lb,
                       float* __restrict__ Wp) {
    int gs = gridDim.x * blockDim.x;
    int g0 = blockIdx.x * blockDim.x + threadIdx.x;
    float* WintX = Wp;
    float* WlX   = Wp + 4096;
    float* btX   = Wp + 7168;
    float* WintY = Wp + 7200;
    float* WlY   = Wp + 11296;
    float* btY   = Wp + 14368;
    h16*   Why   = (h16*)(Wp + 14400);   // 6144 halves = 3072 floats
    for (int j = g0; j < 1024; j += gs) {
        int k = j >> 5, f = j & 31;
        for (int m = 0; m < 3; m++) {
            WintX[j * 4 + m] = th_mw[m * 1024 + f * 32 + k];
            WintY[j * 4 + m] = ga_mw[m * 1024 + f * 32 + k];
        }
        WintX[j * 4 + 3] = 0.f;
        WintY[j * 4 + 3] = 0.f;
    }
    for (int j = g0; j < 3072; j += gs) {
        int i = j >> 10, k = (j >> 5) & 31, f = j & 31;
        WlX[j] = th_lw[i * 1024 + f * 32 + k];
        WlY[j] = ga_lw[i * 1024 + f * 32 + k];
    }
    for (int t = g0; t < 6144; t += gs) {
        int m2h = t >> 9;        // 0..11
        int l   = (t >> 3) & 63; // lane
        int jj  = t & 7;
        int m = m2h >> 1, h = m2h & 1;
        int f = h * 16 + (l & 15);
        int k = ((l >> 4) << 3) + jj;
        float v = (m < 3) ? ga_mw[m * 1024 + f * 32 + k]
                          : ga_lw[(m - 3) * 1024 + f * 32 + k];
        Why[t] = (h16)v;
    }
    for (int f = g0; f < 32; f += gs) {
        float bx = 0.f, by = 0.f;
        for (int m = 0; m < 3; m++) {
            bx += th_mb[m * 32 + f] + th_lb[m * 32 + f];
            by += ga_mb[m * 32 + f] + ga_lb[m * 32 + f];
        }
        btX[f] = bx;
        btY[f] = by;
    }
}

// ---------------- fp32 -> fp16 bulk convert ----------------
__global__ __launch_bounds__(256) void f2h_k(const float* __restrict__ in,
                                             h16* __restrict__ out, int nq) {
    int i = blockIdx.x * 256 + threadIdx.x;
    if (i >= nq) return;
    float4 v = ((const float4*)in)[i];
    h16x4 h;
    h.x = (h16)v.x; h.y = (h16)v.y; h.z = (h16)v.z; h.w = (h16)v.w;
    ((h16x4*)out)[i] = h;
}

// ---------------- g-graph CSR build (small, keep atomic path) ----------------
__global__ __launch_bounds__(256) void hist_k(const int* __restrict__ dst, int ne,
                                              int* __restrict__ counts) {
    int i = blockIdx.x * 256 + threadIdx.x;
    if (i < ne) atomicAdd(&counts[dst[i]], 1);
}

__global__ __launch_bounds__(256) void scan_block_k(const int* __restrict__ counts, int n,
                                                    int* __restrict__ rowptr,
                                                    int* __restrict__ bsums) {
    __shared__ int s[256];
    int tid = threadIdx.x;
    int b0 = blockIdx.x * SCAN_CHUNK;
    int v[8], tsum = 0;
#pragma unroll
    for (int j = 0; j < 8; j++) {
        int idx = b0 + tid * 8 + j;
        v[j] = (idx < n) ? counts[idx] : 0;
        tsum += v[j];
    }
    s[tid] = tsum;
    __syncthreads();
    for (int off = 1; off < 256; off <<= 1) {
        int t = (tid >= off) ? s[tid - off] : 0;
        __syncthreads();
        s[tid] += t;
        __syncthreads();
    }
    int run = s[tid] - tsum;
#pragma unroll
    for (int j = 0; j < 8; j++) {
        int idx = b0 + tid * 8 + j;
        if (idx < n) rowptr[idx] = run;
        run += v[j];
    }
    if (tid == 255) bsums[blockIdx.x] = s[255];
}

__global__ void scan_bsums_k(int* __restrict__ bsums, int nb) {
    __shared__ int s[256];
    int tid = threadIdx.x;
    int v = (tid < nb) ? bsums[tid] : 0;
    s[tid] = v;
    __syncthreads();
    for (int off = 1; off < 256; off <<= 1) {
        int t = (tid >= off) ? s[tid - off] : 0;
        __syncthreads();
        s[tid] += t;
        __syncthreads();
    }
    if (tid < nb) bsums[tid] = s[tid] - v;
}

__global__ __launch_bounds__(256) void scan_add_k(int* __restrict__ rowptr, int n, int ne,
                                                  const int* __restrict__ bsums) {
    int i = blockIdx.x * 256 + threadIdx.x;
    if (i < n) rowptr[i] += bsums[i / SCAN_CHUNK];
    if (i == 0) rowptr[n] = ne;
}

__global__ __launch_bounds__(256) void scatter_g_k(const int* __restrict__ src,
                                                   const int* __restrict__ dst, int ne,
                                                   int* __restrict__ cursor,
                                                   int* __restrict__ cs, int* __restrict__ ce) {
    int i = blockIdx.x * 256 + threadIdx.x;
    if (i >= ne) return;
    int p = atomicAdd(&cursor[dst[i]], 1);
    cs[p] = src[i];
    ce[p] = i;
}

// ---------------- lg CSR build: partitioned, write-amplification-free ----------------
__global__ __launch_bounds__(256) void bucket_hist_k(const int* __restrict__ dst, int ne,
                                                     int* __restrict__ bcnt, int nbuk) {
    __shared__ int h[1024];
    for (int i = threadIdx.x; i < nbuk; i += 256) h[i] = 0;
    __syncthreads();
    for (int i = blockIdx.x * 256 + threadIdx.x; i < ne; i += gridDim.x * 256)
        atomicAdd(&h[dst[i] >> BSH], 1);
    __syncthreads();
    for (int i = threadIdx.x; i < nbuk; i += 256)
        if (h[i]) atomicAdd(&bcnt[i], h[i]);
}

// single block: exclusive scan of bcnt -> bstart (+cursorA copy); nbuk <= 1024
__global__ void bucket_scan_k(const int* __restrict__ bcnt, int nbuk, int ne,
                              int* __restrict__ bstart, int* __restrict__ cursorA) {
    __shared__ int psum[256];
    int tid = threadIdx.x;
    int v[4], s = 0;
#pragma unroll
    for (int j = 0; j < 4; j++) {
        int idx = tid * 4 + j;
        v[j] = (idx < nbuk) ? bcnt[idx] : 0;
        s += v[j];
    }
    psum[tid] = s;
    __syncthreads();
    for (int o = 1; o < 256; o <<= 1) {
        int t = (tid >= o) ? psum[tid - o] : 0;
        __syncthreads();
        psum[tid] += t;
        __syncthreads();
    }
    int run = psum[tid] - s;
#pragma unroll
    for (int j = 0; j < 4; j++) {
        int idx = tid * 4 + j;
        if (idx < nbuk) { bstart[idx] = run; cursorA[idx] = run; }
        run += v[j];
    }
    if (tid == 0) bstart[nbuk] = ne;
}

// phase A: per-tile LDS histogram -> block-reserve runs -> packed uint writes.
// R6: TILEE=2048 (4x blocks, occupancy was 13%), buf packed (src<<BSH)|lo
// (src<2^19, BSH=10 -> 29 bits) halving scatter-write bytes.
__global__ __launch_bounds__(256) void partA_k(const int* __restrict__ src,
                                               const int* __restrict__ dst, int ne,
                                               int* __restrict__ cursorA,
                                               unsigned* __restrict__ buf, int nbuk) {
    __shared__ int h[1024];
    __shared__ int base[1024];
    int t0 = blockIdx.x * TILEE;
    int tend = t0 + TILEE < ne ? t0 + TILEE : ne;
    for (int i = threadIdx.x; i < nbuk; i += 256) h[i] = 0;
    __syncthreads();
    for (int i = t0 + threadIdx.x; i < tend; i += 256)
        atomicAdd(&h[dst[i] >> BSH], 1);
    __syncthreads();
    for (int i = threadIdx.x; i < nbuk; i += 256) {
        int c = h[i];
        base[i] = c ? atomicAdd(&cursorA[i], c) : 0;
        h[i] = 0;  // reuse as block-local cursor
    }
    __syncthreads();
    for (int i = t0 + threadIdx.x; i < tend; i += 256) {
        int d = dst[i];
        int bkt = d >> BSH;
        int pos = base[bkt] + atomicAdd(&h[bkt], 1);
        buf[pos] = ((unsigned)src[i] << BSH) | (unsigned)(d & (BDST - 1));
    }
}

// phase B: one block per bucket; per-dst count+scan in LDS, write cs into the
// bucket's private contiguous region; also emits rowptr for this bucket.
// R6: BDST=1024 (2x blocks, half serial work), packed-uint buf.
__global__ __launch_bounds__(256) void partB_k(const unsigned* __restrict__ buf,
                                               const int* __restrict__ bstart,
                                               int ndst, int ne,
                                               int* __restrict__ cs,
                                               int* __restrict__ rowptr) {
    __shared__ int off[BDST];
    __shared__ int cur[BDST];
    __shared__ int psum[256];
    int b = blockIdx.x;
    int tid = threadIdx.x;
    int lo = bstart[b], hi = bstart[b + 1];
    for (int d = tid; d < BDST; d += 256) { off[d] = 0; cur[d] = 0; }
    __syncthreads();
    for (int i = lo + tid; i < hi; i += 256)
        atomicAdd(&off[buf[i] & (BDST - 1)], 1);
    __syncthreads();
    int base_d = tid * (BDST / 256);
    int loc[BDST / 256], s = 0;
#pragma unroll
    for (int j = 0; j < BDST / 256; j++) { loc[j] = off[base_d + j]; s += loc[j]; }
    psum[tid] = s;
    __syncthreads();
    for (int o = 1; o < 256; o <<= 1) {
        int t = (tid >= o) ? psum[tid - o] : 0;
        __syncthreads();
        psum[tid] += t;
        __syncthreads();
    }
    int run = psum[tid] - s;
#pragma unroll
    for (int j = 0; j < BDST / 256; j++) { int c = loc[j]; off[base_d + j] = run; run += c; }
    __syncthreads();
    int dbase = b << BSH;
    for (int d = tid; d < BDST; d += 256) {
        int gd = dbase + d;
        if (gd < ndst) rowptr[gd] = lo + off[d];
    }
    if (b == 0 && tid == 0) rowptr[ndst] = ne;
    for (int i = lo + tid; i < hi; i += 256) {
        unsigned p = buf[i];
        int ld = (int)(p & (BDST - 1));
        int pos = lo + off[ld] + atomicAdd(&cur[ld], 1);
        cs[pos] = (int)(p >> BSH);
    }
}

// ---------------- pull SPMM: 8 rows/wave, 8 lanes/row ----------------
// R4: 4 gathers in flight, zero shuffles, coalesced stores (attacks
// transaction latency, which R3 proved is the binding constraint).
template <typename TI, typename TO>
__global__ __launch_bounds__(256) void spmm_g_k(const TI* __restrict__ z,
                                                const int* __restrict__ idx,
                                                const int* __restrict__ rowptr,
                                                TO* __restrict__ out, int n) {
    int wave = (blockIdx.x * 256 + threadIdx.x) >> 6;
    int lane = threadIdx.x & 63;
    int g = lane >> 3;
    int lg = lane & 7;
    int row = wave * 8 + g;
    if (row >= n) return;
    int fg = lg * 4;
    int b = rowptr[row], e = rowptr[row + 1];
    float4 acc = make_float4(0.f, 0.f, 0.f, 0.f);
    int i = b;
    for (; i + 4 <= e; i += 4) {
        int i0 = idx[i], i1 = idx[i + 1], i2 = idx[i + 2], i3 = idx[i + 3];
        float4 v0 = load4(z + (size_t)i0 * F + fg);
        float4 v1 = load4(z + (size_t)i1 * F + fg);
        float4 v2 = load4(z + (size_t)i2 * F + fg);
        float4 v3 = load4(z + (size_t)i3 * F + fg);
        acc.x += (v0.x + v1.x) + (v2.x + v3.x);
        acc.y += (v0.y + v1.y) + (v2.y + v3.y);
        acc.z += (v0.z + v1.z) + (v2.z + v3.z);
        acc.w += (v0.w + v1.w) + (v2.w + v3.w);
    }
    for (; i < e; i++) {
        float4 v = load4(z + (size_t)idx[i] * F + fg);
        acc.x += v.x; acc.y += v.y; acc.z += v.z; acc.w += v.w;
    }
    store4(out + (size_t)row * F + fg, acc);
}

// ---------------- y-side mega-GEMM via MFMA (R5, verified) ----------------
__global__ __launch_bounds__(256) void mfma_y_k(
    const float* __restrict__ y, const float* __restrict__ deg,
    const float* __restrict__ x, const int* __restrict__ pm_pd,
    const h16* __restrict__ z1, const h16* __restrict__ z2,
    const h16* __restrict__ z4,
    const h16* __restrict__ Why, const float* __restrict__ bt,
    float* __restrict__ acc, int n)
{
    int wave = (blockIdx.x * 256 + threadIdx.x) >> 6;
    int lane = threadIdx.x & 63;
    int r0 = wave * 16;
    if (r0 >= n) return;

    int row = r0 + (lane & 15);
    int kq = lane >> 4;                 // k-offset = kq*8

    h16x8 B[12];
#pragma unroll
    for (int m = 0; m < 12; m++)
        B[m] = *(const h16x8*)(Why + ((size_t)m * 64 + lane) * 8);

    const float* yp = y + (size_t)row * F + kq * 8;
    float4 ylo = *(const float4*)yp;
    float4 yhi = *(const float4*)(yp + 4);
    float dg = deg[row];
    h16x8 Ay, Ady;
    Ay[0] = (h16)ylo.x; Ay[1] = (h16)ylo.y; Ay[2] = (h16)ylo.z; Ay[3] = (h16)ylo.w;
    Ay[4] = (h16)yhi.x; Ay[5] = (h16)yhi.y; Ay[6] = (h16)yhi.z; Ay[7] = (h16)yhi.w;
    Ady[0] = (h16)(ylo.x * dg); Ady[1] = (h16)(ylo.y * dg);
    Ady[2] = (h16)(ylo.z * dg); Ady[3] = (h16)(ylo.w * dg);
    Ady[4] = (h16)(yhi.x * dg); Ady[5] = (h16)(yhi.y * dg);
    Ady[6] = (h16)(yhi.z * dg); Ady[7] = (h16)(yhi.w * dg);

    int xi = pm_pd[row];
    const float* xp = x + (size_t)xi * F + kq * 8;
    float4 xlo = *(const float4*)xp;
    float4 xhi = *(const float4*)(xp + 4);
    h16x8 Ax;
    Ax[0] = (h16)xlo.x; Ax[1] = (h16)xlo.y; Ax[2] = (h16)xlo.z; Ax[3] = (h16)xlo.w;
    Ax[4] = (h16)xhi.x; Ax[5] = (h16)xhi.y; Ax[6] = (h16)xhi.z; Ax[7] = (h16)xhi.w;

    h16x8 Az1 = *(const h16x8*)(z1 + (size_t)row * F + kq * 8);
    h16x8 Az2 = *(const h16x8*)(z2 + (size_t)row * F + kq * 8);
    h16x8 Az4 = *(const h16x8*)(z4 + (size_t)row * F + kq * 8);

    f32x4 c0 = {0.f, 0.f, 0.f, 0.f};
    f32x4 c1 = {0.f, 0.f, 0.f, 0.f};
    c0 = __builtin_amdgcn_mfma_f32_16x16x32_f16(Ay,  B[0],  c0, 0, 0, 0);
    c1 = __builtin_amdgcn_mfma_f32_16x16x32_f16(Ay,  B[1],  c1, 0, 0, 0);
    c0 = __builtin_amdgcn_mfma_f32_16x16x32_f16(Ady, B[2],  c0, 0, 0, 0);
    c1 = __builtin_amdgcn_mfma_f32_16x16x32_f16(Ady, B[3],  c1, 0, 0, 0);
    c0 = __builtin_amdgcn_mfma_f32_16x16x32_f16(Ax,  B[4],  c0, 0, 0, 0);
    c1 = __builtin_amdgcn_mfma_f32_16x16x32_f16(Ax,  B[5],  c1, 0, 0, 0);
    c0 = __builtin_amdgcn_mfma_f32_16x16x32_f16(Az1, B[6],  c0, 0, 0, 0);
    c1 = __builtin_amdgcn_mfma_f32_16x16x32_f16(Az1, B[7],  c1, 0, 0, 0);
    c0 = __builtin_amdgcn_mfma_f32_16x16x32_f16(Az2, B[8],  c0, 0, 0, 0);
    c1 = __builtin_amdgcn_mfma_f32_16x16x32_f16(Az2, B[9],  c1, 0, 0, 0);
    c0 = __builtin_amdgcn_mfma_f32_16x16x32_f16(Az4, B[10], c0, 0, 0, 0);
    c1 = __builtin_amdgcn_mfma_f32_16x16x32_f16(Az4, B[11], c1, 0, 0, 0);

    float bt0 = bt[lane & 15];
    float bt1 = bt[16 + (lane & 15)];
    int rc = r0 + (lane >> 4) * 4;
#pragma unroll
    for (int j = 0; j < 4; j++) {
        acc[(size_t)(rc + j) * F + (lane & 15)]      = c0[j] + bt0;
        acc[(size_t)(rc + j) * F + 16 + (lane & 15)] = c1[j] + bt1;
    }
}

// ---------------- main linear, 32 rows/block (x side only) ----------------
__global__ __launch_bounds__(256, 4) void main_linear_k(
    const float* __restrict__ in0, const float* __restrict__ deg,
    const float* __restrict__ aux32, const float* __restrict__ auxsrc,
    const int* __restrict__ auxidx,
    const float* __restrict__ Wint_g, const float* __restrict__ bt,
    float* __restrict__ acc, int R)
{
    __shared__ float Wint[4096];
    __shared__ float srow_t[32 * 36];
    __shared__ float arow_t[32 * 36];
    __shared__ float sdeg[32];

    int tid = threadIdx.x;
    int base = blockIdx.x * 32;
    int r = tid >> 3;
    int c = (tid & 7) * 4;
    int row = base + r;

    int arow = row;
    if (!aux32 && row < R) arow = auxidx[row];
    float4 sv = make_float4(0.f, 0.f, 0.f, 0.f);
    float4 av = make_float4(0.f, 0.f, 0.f, 0.f);
    if (row < R) {
        sv = *(const float4*)(in0 + (size_t)row * F + c);
        if (aux32) av = *(const float4*)(aux32 + (size_t)row * F + c);
        else       av = *(const float4*)(auxsrc + (size_t)arow * F + c);
    }
    {
        const float4* g4 = (const float4*)Wint_g;
        float4* s4 = (float4*)Wint;
#pragma unroll
        for (int i = 0; i < 4; i++) s4[tid + i * 256] = g4[tid + i * 256];
    }
    srow_t[(c + 0) * 36 + r] = sv.x;
    srow_t[(c + 1) * 36 + r] = sv.y;
    srow_t[(c + 2) * 36 + r] = sv.z;
    srow_t[(c + 3) * 36 + r] = sv.w;
    arow_t[(c + 0) * 36 + r] = av.x;
    arow_t[(c + 1) * 36 + r] = av.y;
    arow_t[(c + 2) * 36 + r] = av.z;
    arow_t[(c + 3) * 36 + r] = av.w;
    if (tid < 32) sdeg[tid] = (base + tid < R) ? deg[base + tid] : 0.f;
    __syncthreads();

    int f = tid & 31, lr = tid >> 5;
    int r0 = lr * 4;
    float a0[4] = {0.f, 0.f, 0.f, 0.f};
    float a1[4] = {0.f, 0.f, 0.f, 0.f};
    float a2[4] = {0.f, 0.f, 0.f, 0.f};
    const float4* W4 = (const float4*)Wint;
#pragma unroll 4
    for (int k = 0; k < 32; k++) {
        float4 w = W4[k * 32 + f];
        float4 s = *(const float4*)(srow_t + k * 36 + r0);
        float4 a = *(const float4*)(arow_t + k * 36 + r0);
        a0[0] = fmaf(s.x, w.x, a0[0]); a1[0] = fmaf(s.x, w.y, a1[0]); a2[0] = fmaf(a.x, w.z, a2[0]);
        a0[1] = fmaf(s.y, w.x, a0[1]); a1[1] = fmaf(s.y, w.y, a1[1]); a2[1] = fmaf(a.y, w.z, a2[1]);
        a0[2] = fmaf(s.z, w.x, a0[2]); a1[2] = fmaf(s.z, w.y, a1[2]); a2[2] = fmaf(a.z, w.z, a2[2]);
        a0[3] = fmaf(s.w, w.x, a0[3]); a1[3] = fmaf(s.w, w.y, a1[3]); a2[3] = fmaf(a.w, w.z, a2[3]);
    }
    float btf = bt[f];
#pragma unroll
    for (int j = 0; j < 4; j++) {
        int rr = base + r0 + j;
        if (rr < R) acc[(size_t)rr * F + f] = a0[j] + sdeg[r0 + j] * a1[j] + a2[j] + btf;
    }
}

// ---------------- acc += z @ W^T (x side only) ----------------
template <typename TI>
__global__ __launch_bounds__(256, 4) void accum_linear_k(const TI* __restrict__ z,
                                                         const float* __restrict__ Wl,
                                                         float* __restrict__ acc, int R) {
    __shared__ float Wt[1024];
    __shared__ float zt[32 * 36];
    int tid = threadIdx.x;
    int base = blockIdx.x * 32;
    int r = tid >> 3;
    int c = (tid & 7) * 4;
    int row = base + r;
    float4 v = make_float4(0.f, 0.f, 0.f, 0.f);
    if (row < R) v = load4(z + (size_t)row * F + c);
    ((float4*)Wt)[tid] = ((const float4*)Wl)[tid];
    zt[(c + 0) * 36 + r] = v.x;
    zt[(c + 1) * 36 + r] = v.y;
    zt[(c + 2) * 36 + r] = v.z;
    zt[(c + 3) * 36 + r] = v.w;
    __syncthreads();

    int f = tid & 31, lr = tid >> 5;
    int r0 = lr * 4;
    float a[4] = {0.f, 0.f, 0.f, 0.f};
#pragma unroll 4
    for (int k = 0; k < 32; k++) {
        float w = Wt[k * 32 + f];
        float4 s = *(const float4*)(zt + k * 36 + r0);
        a[0] = fmaf(s.x, w, a[0]);
        a[1] = fmaf(s.y, w, a[1]);
        a[2] = fmaf(s.z, w, a[2]);
        a[3] = fmaf(s.w, w, a[3]);
    }
#pragma unroll
    for (int j = 0; j < 4; j++) {
        int rr = base + r0 + j;
        if (rr < R) acc[(size_t)rr * F + f] += a[j];
    }
}

// ---------------- per-column stats of half-ReLU'd acc (read-only) ----------------
__global__ __launch_bounds__(256) void stats_k(const float* __restrict__ acc, int R,
                                               float* __restrict__ stats) {
    int total = R * F;
    int stride = gridDim.x * 256;
    float s = 0.f, ss = 0.f;
    for (int i = blockIdx.x * 256 + threadIdx.x; i < total; i += stride) {
        float v = acc[i];
        if ((i & 31) >= 16) v = fmaxf(v, 0.f);
        s += v;
        ss += v * v;
    }
    __shared__ float Ss[256], Sq[256];
    Ss[threadIdx.x] = s; Sq[threadIdx.x] = ss;
    __syncthreads();
    for (int off = 128; off >= 32; off >>= 1) {
        if (threadIdx.x < off) {
            Ss[threadIdx.x] += Ss[threadIdx.x + off];
            Sq[threadIdx.x] += Sq[threadIdx.x + off];
        }
        __syncthreads();
    }
    if (threadIdx.x < 32) {
        atomicAdd(&stats[threadIdx.x], Ss[threadIdx.x]);
        atomicAdd(&stats[32 + threadIdx.x], Sq[threadIdx.x]);
    }
}

__global__ void scalebias_k(const float* __restrict__ stats,
                            const float* __restrict__ sc_x, const float* __restrict__ bi_x,
                            const float* __restrict__ sc_y, const float* __restrict__ bi_y,
                            float* __restrict__ sb, int Rx, int Ry) {
    int tid = threadIdx.x;
    if (tid >= 64) return;
    int side = tid >> 5, f = tid & 31;
    const float* st = stats + side * 64;
    float Rn = side ? (float)Ry : (float)Rx;
    float mean = st[f] / Rn;
    float var = st[32 + f] / Rn - mean * mean;
    float a = rsqrtf(var + BN_EPS) * (side ? sc_y[f] : sc_x[f]);
    float b = (side ? bi_y[f] : bi_x[f]) - mean * a;
    sb[side * 64 + f] = a;
    sb[side * 64 + 32 + f] = b;
}

// applies the deferred half-ReLU, then the folded BN scale/bias
__global__ __launch_bounds__(256) void finalize_k(const float* __restrict__ acc,
                                                  const float* __restrict__ sb,
                                                  float* __restrict__ out, int R) {
    int i = blockIdx.x * 256 + threadIdx.x;
    if (i >= R * F) return;
    int f = i & 31;
    float v = acc[i];
    if (f >= 16) v = fmaxf(v, 0.f);
    out[i] = v * sb[f] + sb[32 + f];
}

extern "C" void kernel_launch(void* const* d_in, const int* in_sizes, int n_in,
                              void* d_out, int out_size, void* d_ws, size_t ws_size,
                              hipStream_t stream) {
    const float* x       = (const float*)d_in[0];
    const float* y       = (const float*)d_in[1];
    const float* deg_g   = (const float*)d_in[2];
    const float* deg_lg  = (const float*)d_in[3];
    const float* th_mw   = (const float*)d_in[4];
    const float* th_mb   = (const float*)d_in[5];
    const float* th_lw   = (const float*)d_in[6];
    const float* th_lb   = (const float*)d_in[7];
    const float* ga_mw   = (const float*)d_in[8];
    const float* ga_mb   = (const float*)d_in[9];
    const float* ga_lw   = (const float*)d_in[10];
    const float* ga_lb   = (const float*)d_in[11];
    const float* bn_x_sc = (const float*)d_in[12];
    const float* bn_x_bi = (const float*)d_in[13];
    const float* bn_y_sc = (const float*)d_in[14];
    const float* bn_y_bi = (const float*)d_in[15];
    const int*   g_src   = (const int*)d_in[16];
    const int*   g_dst   = (const int*)d_in[17];
    const int*   lg_src  = (const int*)d_in[18];
    const int*   lg_dst  = (const int*)d_in[19];
    const int*   pm_pd   = (const int*)d_in[20];
    float* out = (float*)d_out;

    const int N  = in_sizes[0] / F;
    const int E  = in_sizes[1] / F;
    const int LE = in_sizes[18];
    const int nbuk = (E + BDST - 1) >> BSH;

    // ---- workspace ----
    float* ws    = (float*)d_ws;
    float* stats = ws;                  // 128
    float* sb    = ws + 128;            // 128
    float* Wp    = ws + 256;            // 14400 fp32 + 3072 (Why fp16)
    float* zA_x  = ws + 256 + 17472;
    float* zB_x  = zA_x + (size_t)N * F;
    float* acc_x = zB_x + (size_t)N * F;
    float* pmpd  = acc_x + (size_t)N * F;
    float* zA_y  = pmpd + (size_t)N * F;   // fp16 zh1 + fp16 yh(->zh4)
    float* zB_y  = zA_y + (size_t)E * F;   // fp16 zh2 + fp16 zh3 (aliases buf)
    float* acc_y = zB_y + (size_t)E * F;
    int* ip        = (int*)(acc_y + (size_t)E * F);
    int* rowptr_g  = ip;                    // N+1
    int* counts_g  = rowptr_g + (N + 1);    // N
    int* cs_g      = counts_g + N;          // E
    int* ce_g      = cs_g + E;              // E
    int* rowptr_lg = ce_g + E;              // E+1
    int* cs_lg     = rowptr_lg + (E + 1);   // LE
    int* bcnt      = cs_lg + LE;            // 1024
    int* bstart    = bcnt + 1024;           // 1025
    int* cursorA   = bstart + 1025;         // 1024
    int* bsums_g   = cursorA + 1024;        // 256
    unsigned* buf  = (unsigned*)zB_y;       // LE uint (dead after partB)

    // fp16 views. Lifetimes: yh consumed by pmpd-spmm + h1; h4 overwrites it.
    h16* zh1 = (h16*)zA_y;                        // E*F halves
    h16* yh  = (h16*)(zA_y + (size_t)E * F / 2);  // E*F halves
    h16* zh2 = (h16*)zB_y;                        // E*F halves (buf dead before h2)
    h16* zh3 = (h16*)(zB_y + (size_t)E * F / 2);  // E*F halves
    h16* zh4 = yh;                                // reuse after h1

    const float* WintX = Wp;
    const float* WlX   = Wp + 4096;
    const float* btX   = Wp + 7168;
    const float* btY   = Wp + 14368;
    const h16*   Why   = (const h16*)(Wp + 14400);

    const int nrx = (N + 31) / 32;
    const int pull_gx = (N + 31) / 32;  // 4 waves/block, 8 rows/wave
    const int pull_gy = (E + 31) / 32;
    const int mfma_gy = (E + 63) / 64;  // 4 waves/block, 16 rows/wave
    const int nbs_g = (N + SCAN_CHUNK - 1) / SCAN_CHUNK;

    prep_k<<<16, 256, 0, stream>>>(th_mw, th_mb, th_lw, th_lb,
                                   ga_mw, ga_mb, ga_lw, ga_lb, Wp);
    hipMemsetAsync(stats, 0, 128 * sizeof(float), stream);
    hipMemsetAsync(counts_g, 0, (size_t)N * sizeof(int), stream);
    hipMemsetAsync(bcnt, 0, 1024 * sizeof(int), stream);

    // fp16 copy of y (gather table for pmpd_y + y-h1)
    f2h_k<<<(E * F / 4 + 255) / 256, 256, 0, stream>>>(y, yh, E * F / 4);

    // ---- CSR build: g (atomic path) ----
    hist_k<<<(E + 255) / 256, 256, 0, stream>>>(g_dst, E, counts_g);
    scan_block_k<<<nbs_g, 256, 0, stream>>>(counts_g, N, rowptr_g, bsums_g);
    scan_bsums_k<<<1, 256, 0, stream>>>(bsums_g, nbs_g);
    scan_add_k<<<(N + 255) / 256, 256, 0, stream>>>(rowptr_g, N, E, bsums_g);
    hipMemcpyAsync(counts_g, rowptr_g, (size_t)N * sizeof(int),
                   hipMemcpyDeviceToDevice, stream);
    scatter_g_k<<<(E + 255) / 256, 256, 0, stream>>>(g_src, g_dst, E,
                                                     counts_g, cs_g, ce_g);

    // ---- CSR build: lg (partitioned) ----
    bucket_hist_k<<<1024, 256, 0, stream>>>(lg_dst, LE, bcnt, nbuk);
    bucket_scan_k<<<1, 256, 0, stream>>>(bcnt, nbuk, LE, bstart, cursorA);
    partA_k<<<(LE + TILEE - 1) / TILEE, 256, 0, stream>>>(lg_src, lg_dst, LE,
                                                          cursorA, buf, nbuk);
    partB_k<<<nbuk, 256, 0, stream>>>(buf, bstart, E, LE, cs_lg, rowptr_lg);

    // ---------- x side (fp32 scalar path; x table is L2-resident) ----------
    spmm_g_k<h16, float><<<pull_gx, 256, 0, stream>>>(yh, ce_g, rowptr_g,
                                                      pmpd, N);                  // pmpd_y
    main_linear_k<<<nrx, 256, 0, stream>>>(x, deg_g, pmpd, nullptr, nullptr,
                                           WintX, btX, acc_x, N);
    spmm_g_k<float, float><<<pull_gx, 256, 0, stream>>>(x, cs_g, rowptr_g,
                                                        zA_x, N);                // h1
    accum_linear_k<float><<<nrx, 256, 0, stream>>>(zA_x, WlX, acc_x, N);
    spmm_g_k<float, float><<<pull_gx, 256, 0, stream>>>(zA_x, cs_g, rowptr_g,
                                                        zB_x, N);                // h2
    accum_linear_k<float><<<nrx, 256, 0, stream>>>(zB_x, WlX + 1024, acc_x, N);
    spmm_g_k<float, float><<<pull_gx, 256, 0, stream>>>(zB_x, cs_g, rowptr_g,
                                                        zA_x, N);                // h3
    spmm_g_k<float, float><<<pull_gx, 256, 0, stream>>>(zA_x, cs_g, rowptr_g,
                                                        zB_x, N);                // h4
    accum_linear_k<float><<<nrx, 256, 0, stream>>>(zB_x, WlX + 2048, acc_x, N);
    stats_k<<<512, 256, 0, stream>>>(acc_x, N, stats);

    // ---------- y side: spmm chain then one MFMA mega-GEMM ----------
    spmm_g_k<h16, h16><<<pull_gy, 256, 0, stream>>>(yh, cs_lg, rowptr_lg,
                                                    zh1, E);                     // h1
    spmm_g_k<h16, h16><<<pull_gy, 256, 0, stream>>>(zh1, cs_lg, rowptr_lg,
                                                    zh2, E);                     // h2
    spmm_g_k<h16, h16><<<pull_gy, 256, 0, stream>>>(zh2, cs_lg, rowptr_lg,
                                                    zh3, E);                     // h3
    spmm_g_k<h16, h16><<<pull_gy, 256, 0, stream>>>(zh3, cs_lg, rowptr_lg,
                                                    zh4, E);                     // h4 (into yh slot)
    mfma_y_k<<<mfma_gy, 256, 0, stream>>>(y, deg_lg, x, pm_pd,
                                          zh1, zh2, zh4, Why, btY, acc_y, E);
    stats_k<<<1024, 256, 0, stream>>>(acc_y, E, stats + 64);

    // ---------- BN fold + write ----------
    scalebias_k<<<1, 64, 0, stream>>>(stats, bn_x_sc, bn_x_bi, bn_y_sc, bn_y_bi,
                                      sb, N, E);
    finalize_k<<<(N * F + 255) / 256, 256, 0, stream>>>(acc_x, sb, out, N);
    finalize_k<<<(E * F + 255) / 256, 256, 0, stream>>>(acc_y, sb + 64,
                                                        out + (size_t)N * F, E);
}

// Round 7
// 805.912 us; speedup vs baseline: 1.0544x; 1.0544x over previous
//
#include <hip/hip_runtime.h>

#define F 32
#define BN_EPS 1e-5f
#define SCAN_CHUNK 2048
#define BSH 11
#define BDST (1 << BSH)   // dsts per bucket (R7: back to 2048 — long write runs)
#define TILEE 8192        // edges per partition block (R7: back to 8192)

// fp16 storage type for y-side intermediates (accumulate always fp32).
typedef _Float16 h16;
typedef __attribute__((ext_vector_type(4))) _Float16 h16x4;
typedef __attribute__((ext_vector_type(8))) _Float16 h16x8;
typedef __attribute__((ext_vector_type(4))) float f32x4;

__device__ inline float4 load4(const float* p) { return *(const float4*)p; }
__device__ inline float4 load4(const h16* p) {
    h16x4 h = *(const h16x4*)p;
    return make_float4((float)h.x, (float)h.y, (float)h.z, (float)h.w);
}
__device__ inline void store4(float* p, float4 v) { *(float4*)p = v; }
__device__ inline void store4(h16* p, float4 v) {
    h16x4 h;
    h.x = (h16)v.x; h.y = (h16)v.y; h.z = (h16)v.z; h.w = (h16)v.w;
    *(h16x4*)p = h;
}

// ---------------- weight prep ----------------
// WintX: [k][f][3] padded to 4 for the main-linear float4 LDS path (x side).
// WlX:   Wl[i*1024 + k*32 + f] = w_i[f][k] (accum_linear layout, x side).
// Why:   fp16 MFMA B-fragments for the y-side mega-GEMM:
//        Why[(m2h)*512 + l*8 + j] = Wm[h*16+(l&15)][(l>>4)*8+j], m2h=m*2+h.
//        Matrix order m: 0=gamma_y 1=gamma_deg 2=gamma_x 3..5=gamma_list.
__global__ void prep_k(const float* __restrict__ th_mw, const float* __restrict__ th_mb,
                       const float* __restrict__ th_lw, const float* __restrict__ th_lb,
                       const float* __restrict__ ga_mw, const float* __restrict__ ga_mb,
                       const float* __restrict__ ga_lw, const float* __restrict__ ga_lb,
                       float* __restrict__ Wp) {
    int gs = gridDim.x * blockDim.x;
    int g0 = blockIdx.x * blockDim.x + threadIdx.x;
    float* WintX = Wp;
    float* WlX   = Wp + 4096;
    float* btX   = Wp + 7168;
    float* WintY = Wp + 7200;
    float* WlY   = Wp + 11296;
    float* btY   = Wp + 14368;
    h16*   Why   = (h16*)(Wp + 14400);   // 6144 halves = 3072 floats
    for (int j = g0; j < 1024; j += gs) {
        int k = j >> 5, f = j & 31;
        for (int m = 0; m < 3; m++) {
            WintX[j * 4 + m] = th_mw[m * 1024 + f * 32 + k];
            WintY[j * 4 + m] = ga_mw[m * 1024 + f * 32 + k];
        }
        WintX[j * 4 + 3] = 0.f;
        WintY[j * 4 + 3] = 0.f;
    }
    for (int j = g0; j < 3072; j += gs) {
        int i = j >> 10, k = (j >> 5) & 31, f = j & 31;
        WlX[j] = th_lw[i * 1024 + f * 32 + k];
        WlY[j] = ga_lw[i * 1024 + f * 32 + k];
    }
    for (int t = g0; t < 6144; t += gs) {
        int m2h = t >> 9;        // 0..11
        int l   = (t >> 3) & 63; // lane
        int jj  = t & 7;
        int m = m2h >> 1, h = m2h & 1;
        int f = h * 16 + (l & 15);
        int k = ((l >> 4) << 3) + jj;
        float v = (m < 3) ? ga_mw[m * 1024 + f * 32 + k]
                          : ga_lw[(m - 3) * 1024 + f * 32 + k];
        Why[t] = (h16)v;
    }
    for (int f = g0; f < 32; f += gs) {
        float bx = 0.f, by = 0.f;
        for (int m = 0; m < 3; m++) {
            bx += th_mb[m * 32 + f] + th_lb[m * 32 + f];
            by += ga_mb[m * 32 + f] + ga_lb[m * 32 + f];
        }
        btX[f] = bx;
        btY[f] = by;
    }
}

// ---------------- fp32 -> fp16 bulk convert ----------------
__global__ __launch_bounds__(256) void f2h_k(const float* __restrict__ in,
                                             h16* __restrict__ out, int nq) {
    int i = blockIdx.x * 256 + threadIdx.x;
    if (i >= nq) return;
    float4 v = ((const float4*)in)[i];
    h16x4 h;
    h.x = (h16)v.x; h.y = (h16)v.y; h.z = (h16)v.z; h.w = (h16)v.w;
    ((h16x4*)out)[i] = h;
}

// ---------------- g-graph CSR build (small, keep atomic path) ----------------
__global__ __launch_bounds__(256) void hist_k(const int* __restrict__ dst, int ne,
                                              int* __restrict__ counts) {
    int i = blockIdx.x * 256 + threadIdx.x;
    if (i < ne) atomicAdd(&counts[dst[i]], 1);
}

__global__ __launch_bounds__(256) void scan_block_k(const int* __restrict__ counts, int n,
                                                    int* __restrict__ rowptr,
                                                    int* __restrict__ bsums) {
    __shared__ int s[256];
    int tid = threadIdx.x;
    int b0 = blockIdx.x * SCAN_CHUNK;
    int v[8], tsum = 0;
#pragma unroll
    for (int j = 0; j < 8; j++) {
        int idx = b0 + tid * 8 + j;
        v[j] = (idx < n) ? counts[idx] : 0;
        tsum += v[j];
    }
    s[tid] = tsum;
    __syncthreads();
    for (int off = 1; off < 256; off <<= 1) {
        int t = (tid >= off) ? s[tid - off] : 0;
        __syncthreads();
        s[tid] += t;
        __syncthreads();
    }
    int run = s[tid] - tsum;
#pragma unroll
    for (int j = 0; j < 8; j++) {
        int idx = b0 + tid * 8 + j;
        if (idx < n) rowptr[idx] = run;
        run += v[j];
    }
    if (tid == 255) bsums[blockIdx.x] = s[255];
}

__global__ void scan_bsums_k(int* __restrict__ bsums, int nb) {
    __shared__ int s[256];
    int tid = threadIdx.x;
    int v = (tid < nb) ? bsums[tid] : 0;
    s[tid] = v;
    __syncthreads();
    for (int off = 1; off < 256; off <<= 1) {
        int t = (tid >= off) ? s[tid - off] : 0;
        __syncthreads();
        s[tid] += t;
        __syncthreads();
    }
    if (tid < nb) bsums[tid] = s[tid] - v;
}

__global__ __launch_bounds__(256) void scan_add_k(int* __restrict__ rowptr, int n, int ne,
                                                  const int* __restrict__ bsums) {
    int i = blockIdx.x * 256 + threadIdx.x;
    if (i < n) rowptr[i] += bsums[i / SCAN_CHUNK];
    if (i == 0) rowptr[n] = ne;
}

__global__ __launch_bounds__(256) void scatter_g_k(const int* __restrict__ src,
                                                   const int* __restrict__ dst, int ne,
                                                   int* __restrict__ cursor,
                                                   int* __restrict__ cs, int* __restrict__ ce) {
    int i = blockIdx.x * 256 + threadIdx.x;
    if (i >= ne) return;
    int p = atomicAdd(&cursor[dst[i]], 1);
    cs[p] = src[i];
    ce[p] = i;
}

// ---------------- lg CSR build: partitioned, write-amplification-free ----------------
__global__ __launch_bounds__(256) void bucket_hist_k(const int* __restrict__ dst, int ne,
                                                     int* __restrict__ bcnt, int nbuk) {
    __shared__ int h[1024];
    for (int i = threadIdx.x; i < nbuk; i += 256) h[i] = 0;
    __syncthreads();
    for (int i = blockIdx.x * 256 + threadIdx.x; i < ne; i += gridDim.x * 256)
        atomicAdd(&h[dst[i] >> BSH], 1);
    __syncthreads();
    for (int i = threadIdx.x; i < nbuk; i += 256)
        if (h[i]) atomicAdd(&bcnt[i], h[i]);
}

// single block: exclusive scan of bcnt -> bstart (+cursorA copy); nbuk <= 1024
__global__ void bucket_scan_k(const int* __restrict__ bcnt, int nbuk, int ne,
                              int* __restrict__ bstart, int* __restrict__ cursorA) {
    __shared__ int psum[256];
    int tid = threadIdx.x;
    int v[4], s = 0;
#pragma unroll
    for (int j = 0; j < 4; j++) {
        int idx = tid * 4 + j;
        v[j] = (idx < nbuk) ? bcnt[idx] : 0;
        s += v[j];
    }
    psum[tid] = s;
    __syncthreads();
    for (int o = 1; o < 256; o <<= 1) {
        int t = (tid >= o) ? psum[tid - o] : 0;
        __syncthreads();
        psum[tid] += t;
        __syncthreads();
    }
    int run = psum[tid] - s;
#pragma unroll
    for (int j = 0; j < 4; j++) {
        int idx = tid * 4 + j;
        if (idx < nbuk) { bstart[idx] = run; cursorA[idx] = run; }
        run += v[j];
    }
    if (tid == 0) bstart[nbuk] = ne;
}

// phase A: per-tile LDS histogram -> block-reserve runs -> packed uint writes.
// R7: TILEE=8192/BSH=11 restored (R6 proved run length controls write
// amplification: runs of ~5 edges tripled WRITE_SIZE; ~42-edge runs are
// ~1.4x). Packed (src<<BSH)|lo (19+11=30 bits) kept: halves scatter bytes.
__global__ __launch_bounds__(256) void partA_k(const int* __restrict__ src,
                                               const int* __restrict__ dst, int ne,
                                               int* __restrict__ cursorA,
                                               unsigned* __restrict__ buf, int nbuk) {
    __shared__ int h[1024];
    __shared__ int base[1024];
    int t0 = blockIdx.x * TILEE;
    int tend = t0 + TILEE < ne ? t0 + TILEE : ne;
    for (int i = threadIdx.x; i < nbuk; i += 256) h[i] = 0;
    __syncthreads();
    for (int i = t0 + threadIdx.x; i < tend; i += 256)
        atomicAdd(&h[dst[i] >> BSH], 1);
    __syncthreads();
    for (int i = threadIdx.x; i < nbuk; i += 256) {
        int c = h[i];
        base[i] = c ? atomicAdd(&cursorA[i], c) : 0;
        h[i] = 0;  // reuse as block-local cursor
    }
    __syncthreads();
    for (int i = t0 + threadIdx.x; i < tend; i += 256) {
        int d = dst[i];
        int bkt = d >> BSH;
        int pos = base[bkt] + atomicAdd(&h[bkt], 1);
        buf[pos] = ((unsigned)src[i] << BSH) | (unsigned)(d & (BDST - 1));
    }
}

// phase B: one block per bucket; per-dst count+scan in LDS, write cs into the
// bucket's private contiguous region; also emits rowptr for this bucket.
__global__ __launch_bounds__(256) void partB_k(const unsigned* __restrict__ buf,
                                               const int* __restrict__ bstart,
                                               int ndst, int ne,
                                               int* __restrict__ cs,
                                               int* __restrict__ rowptr) {
    __shared__ int off[BDST];
    __shared__ int cur[BDST];
    __shared__ int psum[256];
    int b = blockIdx.x;
    int tid = threadIdx.x;
    int lo = bstart[b], hi = bstart[b + 1];
    for (int d = tid; d < BDST; d += 256) { off[d] = 0; cur[d] = 0; }
    __syncthreads();
    for (int i = lo + tid; i < hi; i += 256)
        atomicAdd(&off[buf[i] & (BDST - 1)], 1);
    __syncthreads();
    int base_d = tid * (BDST / 256);
    int loc[BDST / 256], s = 0;
#pragma unroll
    for (int j = 0; j < BDST / 256; j++) { loc[j] = off[base_d + j]; s += loc[j]; }
    psum[tid] = s;
    __syncthreads();
    for (int o = 1; o < 256; o <<= 1) {
        int t = (tid >= o) ? psum[tid - o] : 0;
        __syncthreads();
        psum[tid] += t;
        __syncthreads();
    }
    int run = psum[tid] - s;
#pragma unroll
    for (int j = 0; j < BDST / 256; j++) { int c = loc[j]; off[base_d + j] = run; run += c; }
    __syncthreads();
    int dbase = b << BSH;
    for (int d = tid; d < BDST; d += 256) {
        int gd = dbase + d;
        if (gd < ndst) rowptr[gd] = lo + off[d];
    }
    if (b == 0 && tid == 0) rowptr[ndst] = ne;
    for (int i = lo + tid; i < hi; i += 256) {
        unsigned p = buf[i];
        int ld = (int)(p & (BDST - 1));
        int pos = lo + off[ld] + atomicAdd(&cur[ld], 1);
        cs[pos] = (int)(p >> BSH);
    }
}

// ---------------- pull SPMM: 8 rows/wave, 8 lanes/row ----------------
// R4: 4 gathers in flight, zero shuffles, coalesced stores (attacks
// transaction latency, which R3 proved is the binding constraint).
template <typename TI, typename TO>
__global__ __launch_bounds__(256) void spmm_g_k(const TI* __restrict__ z,
                                                const int* __restrict__ idx,
                                                const int* __restrict__ rowptr,
                                                TO* __restrict__ out, int n) {
    int wave = (blockIdx.x * 256 + threadIdx.x) >> 6;
    int lane = threadIdx.x & 63;
    int g = lane >> 3;
    int lg = lane & 7;
    int row = wave * 8 + g;
    if (row >= n) return;
    int fg = lg * 4;
    int b = rowptr[row], e = rowptr[row + 1];
    float4 acc = make_float4(0.f, 0.f, 0.f, 0.f);
    int i = b;
    for (; i + 4 <= e; i += 4) {
        int i0 = idx[i], i1 = idx[i + 1], i2 = idx[i + 2], i3 = idx[i + 3];
        float4 v0 = load4(z + (size_t)i0 * F + fg);
        float4 v1 = load4(z + (size_t)i1 * F + fg);
        float4 v2 = load4(z + (size_t)i2 * F + fg);
        float4 v3 = load4(z + (size_t)i3 * F + fg);
        acc.x += (v0.x + v1.x) + (v2.x + v3.x);
        acc.y += (v0.y + v1.y) + (v2.y + v3.y);
        acc.z += (v0.z + v1.z) + (v2.z + v3.z);
        acc.w += (v0.w + v1.w) + (v2.w + v3.w);
    }
    for (; i < e; i++) {
        float4 v = load4(z + (size_t)idx[i] * F + fg);
        acc.x += v.x; acc.y += v.y; acc.z += v.z; acc.w += v.w;
    }
    store4(out + (size_t)row * F + fg, acc);
}

// ---------------- y-side mega-GEMM via MFMA (R5, verified) ----------------
__global__ __launch_bounds__(256) void mfma_y_k(
    const float* __restrict__ y, const float* __restrict__ deg,
    const float* __restrict__ x, const int* __restrict__ pm_pd,
    const h16* __restrict__ z1, const h16* __restrict__ z2,
    const h16* __restrict__ z4,
    const h16* __restrict__ Why, const float* __restrict__ bt,
    float* __restrict__ acc, int n)
{
    int wave = (blockIdx.x * 256 + threadIdx.x) >> 6;
    int lane = threadIdx.x & 63;
    int r0 = wave * 16;
    if (r0 >= n) return;

    int row = r0 + (lane & 15);
    int kq = lane >> 4;                 // k-offset = kq*8

    h16x8 B[12];
#pragma unroll
    for (int m = 0; m < 12; m++)
        B[m] = *(const h16x8*)(Why + ((size_t)m * 64 + lane) * 8);

    const float* yp = y + (size_t)row * F + kq * 8;
    float4 ylo = *(const float4*)yp;
    float4 yhi = *(const float4*)(yp + 4);
    float dg = deg[row];
    h16x8 Ay, Ady;
    Ay[0] = (h16)ylo.x; Ay[1] = (h16)ylo.y; Ay[2] = (h16)ylo.z; Ay[3] = (h16)ylo.w;
    Ay[4] = (h16)yhi.x; Ay[5] = (h16)yhi.y; Ay[6] = (h16)yhi.z; Ay[7] = (h16)yhi.w;
    Ady[0] = (h16)(ylo.x * dg); Ady[1] = (h16)(ylo.y * dg);
    Ady[2] = (h16)(ylo.z * dg); Ady[3] = (h16)(ylo.w * dg);
    Ady[4] = (h16)(yhi.x * dg); Ady[5] = (h16)(yhi.y * dg);
    Ady[6] = (h16)(yhi.z * dg); Ady[7] = (h16)(yhi.w * dg);

    int xi = pm_pd[row];
    const float* xp = x + (size_t)xi * F + kq * 8;
    float4 xlo = *(const float4*)xp;
    float4 xhi = *(const float4*)(xp + 4);
    h16x8 Ax;
    Ax[0] = (h16)xlo.x; Ax[1] = (h16)xlo.y; Ax[2] = (h16)xlo.z; Ax[3] = (h16)xlo.w;
    Ax[4] = (h16)xhi.x; Ax[5] = (h16)xhi.y; Ax[6] = (h16)xhi.z; Ax[7] = (h16)xhi.w;

    h16x8 Az1 = *(const h16x8*)(z1 + (size_t)row * F + kq * 8);
    h16x8 Az2 = *(const h16x8*)(z2 + (size_t)row * F + kq * 8);
    h16x8 Az4 = *(const h16x8*)(z4 + (size_t)row * F + kq * 8);

    f32x4 c0 = {0.f, 0.f, 0.f, 0.f};
    f32x4 c1 = {0.f, 0.f, 0.f, 0.f};
    c0 = __builtin_amdgcn_mfma_f32_16x16x32_f16(Ay,  B[0],  c0, 0, 0, 0);
    c1 = __builtin_amdgcn_mfma_f32_16x16x32_f16(Ay,  B[1],  c1, 0, 0, 0);
    c0 = __builtin_amdgcn_mfma_f32_16x16x32_f16(Ady, B[2],  c0, 0, 0, 0);
    c1 = __builtin_amdgcn_mfma_f32_16x16x32_f16(Ady, B[3],  c1, 0, 0, 0);
    c0 = __builtin_amdgcn_mfma_f32_16x16x32_f16(Ax,  B[4],  c0, 0, 0, 0);
    c1 = __builtin_amdgcn_mfma_f32_16x16x32_f16(Ax,  B[5],  c1, 0, 0, 0);
    c0 = __builtin_amdgcn_mfma_f32_16x16x32_f16(Az1, B[6],  c0, 0, 0, 0);
    c1 = __builtin_amdgcn_mfma_f32_16x16x32_f16(Az1, B[7],  c1, 0, 0, 0);
    c0 = __builtin_amdgcn_mfma_f32_16x16x32_f16(Az2, B[8],  c0, 0, 0, 0);
    c1 = __builtin_amdgcn_mfma_f32_16x16x32_f16(Az2, B[9],  c1, 0, 0, 0);
    c0 = __builtin_amdgcn_mfma_f32_16x16x32_f16(Az4, B[10], c0, 0, 0, 0);
    c1 = __builtin_amdgcn_mfma_f32_16x16x32_f16(Az4, B[11], c1, 0, 0, 0);

    float bt0 = bt[lane & 15];
    float bt1 = bt[16 + (lane & 15)];
    int rc = r0 + (lane >> 4) * 4;
#pragma unroll
    for (int j = 0; j < 4; j++) {
        acc[(size_t)(rc + j) * F + (lane & 15)]      = c0[j] + bt0;
        acc[(size_t)(rc + j) * F + 16 + (lane & 15)] = c1[j] + bt1;
    }
}

// ---------------- main linear, 32 rows/block (x side only) ----------------
__global__ __launch_bounds__(256, 4) void main_linear_k(
    const float* __restrict__ in0, const float* __restrict__ deg,
    const float* __restrict__ aux32, const float* __restrict__ auxsrc,
    const int* __restrict__ auxidx,
    const float* __restrict__ Wint_g, const float* __restrict__ bt,
    float* __restrict__ acc, int R)
{
    __shared__ float Wint[4096];
    __shared__ float srow_t[32 * 36];
    __shared__ float arow_t[32 * 36];
    __shared__ float sdeg[32];

    int tid = threadIdx.x;
    int base = blockIdx.x * 32;
    int r = tid >> 3;
    int c = (tid & 7) * 4;
    int row = base + r;

    int arow = row;
    if (!aux32 && row < R) arow = auxidx[row];
    float4 sv = make_float4(0.f, 0.f, 0.f, 0.f);
    float4 av = make_float4(0.f, 0.f, 0.f, 0.f);
    if (row < R) {
        sv = *(const float4*)(in0 + (size_t)row * F + c);
        if (aux32) av = *(const float4*)(aux32 + (size_t)row * F + c);
        else       av = *(const float4*)(auxsrc + (size_t)arow * F + c);
    }
    {
        const float4* g4 = (const float4*)Wint_g;
        float4* s4 = (float4*)Wint;
#pragma unroll
        for (int i = 0; i < 4; i++) s4[tid + i * 256] = g4[tid + i * 256];
    }
    srow_t[(c + 0) * 36 + r] = sv.x;
    srow_t[(c + 1) * 36 + r] = sv.y;
    srow_t[(c + 2) * 36 + r] = sv.z;
    srow_t[(c + 3) * 36 + r] = sv.w;
    arow_t[(c + 0) * 36 + r] = av.x;
    arow_t[(c + 1) * 36 + r] = av.y;
    arow_t[(c + 2) * 36 + r] = av.z;
    arow_t[(c + 3) * 36 + r] = av.w;
    if (tid < 32) sdeg[tid] = (base + tid < R) ? deg[base + tid] : 0.f;
    __syncthreads();

    int f = tid & 31, lr = tid >> 5;
    int r0 = lr * 4;
    float a0[4] = {0.f, 0.f, 0.f, 0.f};
    float a1[4] = {0.f, 0.f, 0.f, 0.f};
    float a2[4] = {0.f, 0.f, 0.f, 0.f};
    const float4* W4 = (const float4*)Wint;
#pragma unroll 4
    for (int k = 0; k < 32; k++) {
        float4 w = W4[k * 32 + f];
        float4 s = *(const float4*)(srow_t + k * 36 + r0);
        float4 a = *(const float4*)(arow_t + k * 36 + r0);
        a0[0] = fmaf(s.x, w.x, a0[0]); a1[0] = fmaf(s.x, w.y, a1[0]); a2[0] = fmaf(a.x, w.z, a2[0]);
        a0[1] = fmaf(s.y, w.x, a0[1]); a1[1] = fmaf(s.y, w.y, a1[1]); a2[1] = fmaf(a.y, w.z, a2[1]);
        a0[2] = fmaf(s.z, w.x, a0[2]); a1[2] = fmaf(s.z, w.y, a1[2]); a2[2] = fmaf(a.z, w.z, a2[2]);
        a0[3] = fmaf(s.w, w.x, a0[3]); a1[3] = fmaf(s.w, w.y, a1[3]); a2[3] = fmaf(a.w, w.z, a2[3]);
    }
    float btf = bt[f];
#pragma unroll
    for (int j = 0; j < 4; j++) {
        int rr = base + r0 + j;
        if (rr < R) acc[(size_t)rr * F + f] = a0[j] + sdeg[r0 + j] * a1[j] + a2[j] + btf;
    }
}

// ---------------- acc += z @ W^T (x side only) ----------------
template <typename TI>
__global__ __launch_bounds__(256, 4) void accum_linear_k(const TI* __restrict__ z,
                                                         const float* __restrict__ Wl,
                                                         float* __restrict__ acc, int R) {
    __shared__ float Wt[1024];
    __shared__ float zt[32 * 36];
    int tid = threadIdx.x;
    int base = blockIdx.x * 32;
    int r = tid >> 3;
    int c = (tid & 7) * 4;
    int row = base + r;
    float4 v = make_float4(0.f, 0.f, 0.f, 0.f);
    if (row < R) v = load4(z + (size_t)row * F + c);
    ((float4*)Wt)[tid] = ((const float4*)Wl)[tid];
    zt[(c + 0) * 36 + r] = v.x;
    zt[(c + 1) * 36 + r] = v.y;
    zt[(c + 2) * 36 + r] = v.z;
    zt[(c + 3) * 36 + r] = v.w;
    __syncthreads();

    int f = tid & 31, lr = tid >> 5;
    int r0 = lr * 4;
    float a[4] = {0.f, 0.f, 0.f, 0.f};
#pragma unroll 4
    for (int k = 0; k < 32; k++) {
        float w = Wt[k * 32 + f];
        float4 s = *(const float4*)(zt + k * 36 + r0);
        a[0] = fmaf(s.x, w, a[0]);
        a[1] = fmaf(s.y, w, a[1]);
        a[2] = fmaf(s.z, w, a[2]);
        a[3] = fmaf(s.w, w, a[3]);
    }
#pragma unroll
    for (int j = 0; j < 4; j++) {
        int rr = base + r0 + j;
        if (rr < R) acc[(size_t)rr * F + f] += a[j];
    }
}

// ---------------- per-column stats of half-ReLU'd acc (read-only) ----------------
__global__ __launch_bounds__(256) void stats_k(const float* __restrict__ acc, int R,
                                               float* __restrict__ stats) {
    int total = R * F;
    int stride = gridDim.x * 256;
    float s = 0.f, ss = 0.f;
    for (int i = blockIdx.x * 256 + threadIdx.x; i < total; i += stride) {
        float v = acc[i];
        if ((i & 31) >= 16) v = fmaxf(v, 0.f);
        s += v;
        ss += v * v;
    }
    __shared__ float Ss[256], Sq[256];
    Ss[threadIdx.x] = s; Sq[threadIdx.x] = ss;
    __syncthreads();
    for (int off = 128; off >= 32; off >>= 1) {
        if (threadIdx.x < off) {
            Ss[threadIdx.x] += Ss[threadIdx.x + off];
            Sq[threadIdx.x] += Sq[threadIdx.x + off];
        }
        __syncthreads();
    }
    if (threadIdx.x < 32) {
        atomicAdd(&stats[threadIdx.x], Ss[threadIdx.x]);
        atomicAdd(&stats[32 + threadIdx.x], Sq[threadIdx.x]);
    }
}

__global__ void scalebias_k(const float* __restrict__ stats,
                            const float* __restrict__ sc_x, const float* __restrict__ bi_x,
                            const float* __restrict__ sc_y, const float* __restrict__ bi_y,
                            float* __restrict__ sb, int Rx, int Ry) {
    int tid = threadIdx.x;
    if (tid >= 64) return;
    int side = tid >> 5, f = tid & 31;
    const float* st = stats + side * 64;
    float Rn = side ? (float)Ry : (float)Rx;
    float mean = st[f] / Rn;
    float var = st[32 + f] / Rn - mean * mean;
    float a = rsqrtf(var + BN_EPS) * (side ? sc_y[f] : sc_x[f]);
    float b = (side ? bi_y[f] : bi_x[f]) - mean * a;
    sb[side * 64 + f] = a;
    sb[side * 64 + 32 + f] = b;
}

// applies the deferred half-ReLU, then the folded BN scale/bias
__global__ __launch_bounds__(256) void finalize_k(const float* __restrict__ acc,
                                                  const float* __restrict__ sb,
                                                  float* __restrict__ out, int R) {
    int i = blockIdx.x * 256 + threadIdx.x;
    if (i >= R * F) return;
    int f = i & 31;
    float v = acc[i];
    if (f >= 16) v = fmaxf(v, 0.f);
    out[i] = v * sb[f] + sb[32 + f];
}

extern "C" void kernel_launch(void* const* d_in, const int* in_sizes, int n_in,
                              void* d_out, int out_size, void* d_ws, size_t ws_size,
                              hipStream_t stream) {
    const float* x       = (const float*)d_in[0];
    const float* y       = (const float*)d_in[1];
    const float* deg_g   = (const float*)d_in[2];
    const float* deg_lg  = (const float*)d_in[3];
    const float* th_mw   = (const float*)d_in[4];
    const float* th_mb   = (const float*)d_in[5];
    const float* th_lw   = (const float*)d_in[6];
    const float* th_lb   = (const float*)d_in[7];
    const float* ga_mw   = (const float*)d_in[8];
    const float* ga_mb   = (const float*)d_in[9];
    const float* ga_lw   = (const float*)d_in[10];
    const float* ga_lb   = (const float*)d_in[11];
    const float* bn_x_sc = (const float*)d_in[12];
    const float* bn_x_bi = (const float*)d_in[13];
    const float* bn_y_sc = (const float*)d_in[14];
    const float* bn_y_bi = (const float*)d_in[15];
    const int*   g_src   = (const int*)d_in[16];
    const int*   g_dst   = (const int*)d_in[17];
    const int*   lg_src  = (const int*)d_in[18];
    const int*   lg_dst  = (const int*)d_in[19];
    const int*   pm_pd   = (const int*)d_in[20];
    float* out = (float*)d_out;

    const int N  = in_sizes[0] / F;
    const int E  = in_sizes[1] / F;
    const int LE = in_sizes[18];
    const int nbuk = (E + BDST - 1) >> BSH;

    // ---- workspace ----
    float* ws    = (float*)d_ws;
    float* stats = ws;                  // 128
    float* sb    = ws + 128;            // 128
    float* Wp    = ws + 256;            // 14400 fp32 + 3072 (Why fp16)
    float* zA_x  = ws + 256 + 17472;
    float* zB_x  = zA_x + (size_t)N * F;
    float* acc_x = zB_x + (size_t)N * F;
    float* pmpd  = acc_x + (size_t)N * F;
    float* zA_y  = pmpd + (size_t)N * F;   // fp16 zh1 + fp16 yh(->zh4)
    float* zB_y  = zA_y + (size_t)E * F;   // fp16 zh2 + fp16 zh3 (aliases buf)
    float* acc_y = zB_y + (size_t)E * F;
    int* ip        = (int*)(acc_y + (size_t)E * F);
    int* rowptr_g  = ip;                    // N+1
    int* counts_g  = rowptr_g + (N + 1);    // N
    int* cs_g      = counts_g + N;          // E
    int* ce_g      = cs_g + E;              // E
    int* rowptr_lg = ce_g + E;              // E+1
    int* cs_lg     = rowptr_lg + (E + 1);   // LE
    int* bcnt      = cs_lg + LE;            // 1024
    int* bstart    = bcnt + 1024;           // 1025
    int* cursorA   = bstart + 1025;         // 1024
    int* bsums_g   = cursorA + 1024;        // 256
    unsigned* buf  = (unsigned*)zB_y;       // LE uint (dead after partB)

    // fp16 views. Lifetimes: yh consumed by pmpd-spmm + h1; h4 overwrites it.
    h16* zh1 = (h16*)zA_y;                        // E*F halves
    h16* yh  = (h16*)(zA_y + (size_t)E * F / 2);  // E*F halves
    h16* zh2 = (h16*)zB_y;                        // E*F halves (buf dead before h2)
    h16* zh3 = (h16*)(zB_y + (size_t)E * F / 2);  // E*F halves
    h16* zh4 = yh;                                // reuse after h1

    const float* WintX = Wp;
    const float* WlX   = Wp + 4096;
    const float* btX   = Wp + 7168;
    const float* btY   = Wp + 14368;
    const h16*   Why   = (const h16*)(Wp + 14400);

    const int nrx = (N + 31) / 32;
    const int pull_gx = (N + 31) / 32;  // 4 waves/block, 8 rows/wave
    const int pull_gy = (E + 31) / 32;
    const int mfma_gy = (E + 63) / 64;  // 4 waves/block, 16 rows/wave
    const int nbs_g = (N + SCAN_CHUNK - 1) / SCAN_CHUNK;

    prep_k<<<16, 256, 0, stream>>>(th_mw, th_mb, th_lw, th_lb,
                                   ga_mw, ga_mb, ga_lw, ga_lb, Wp);
    hipMemsetAsync(stats, 0, 128 * sizeof(float), stream);
    hipMemsetAsync(counts_g, 0, (size_t)N * sizeof(int), stream);
    hipMemsetAsync(bcnt, 0, 1024 * sizeof(int), stream);

    // fp16 copy of y (gather table for pmpd_y + y-h1)
    f2h_k<<<(E * F / 4 + 255) / 256, 256, 0, stream>>>(y, yh, E * F / 4);

    // ---- CSR build: g (atomic path) ----
    hist_k<<<(E + 255) / 256, 256, 0, stream>>>(g_dst, E, counts_g);
    scan_block_k<<<nbs_g, 256, 0, stream>>>(counts_g, N, rowptr_g, bsums_g);
    scan_bsums_k<<<1, 256, 0, stream>>>(bsums_g, nbs_g);
    scan_add_k<<<(N + 255) / 256, 256, 0, stream>>>(rowptr_g, N, E, bsums_g);
    hipMemcpyAsync(counts_g, rowptr_g, (size_t)N * sizeof(int),
                   hipMemcpyDeviceToDevice, stream);
    scatter_g_k<<<(E + 255) / 256, 256, 0, stream>>>(g_src, g_dst, E,
                                                     counts_g, cs_g, ce_g);

    // ---- CSR build: lg (partitioned) ----
    bucket_hist_k<<<1024, 256, 0, stream>>>(lg_dst, LE, bcnt, nbuk);
    bucket_scan_k<<<1, 256, 0, stream>>>(bcnt, nbuk, LE, bstart, cursorA);
    partA_k<<<(LE + TILEE - 1) / TILEE, 256, 0, stream>>>(lg_src, lg_dst, LE,
                                                          cursorA, buf, nbuk);
    partB_k<<<nbuk, 256, 0, stream>>>(buf, bstart, E, LE, cs_lg, rowptr_lg);

    // ---------- x side (fp32 scalar path; x table is L2-resident) ----------
    spmm_g_k<h16, float><<<pull_gx, 256, 0, stream>>>(yh, ce_g, rowptr_g,
                                                      pmpd, N);                  // pmpd_y
    main_linear_k<<<nrx, 256, 0, stream>>>(x, deg_g, pmpd, nullptr, nullptr,
                                           WintX, btX, acc_x, N);
    spmm_g_k<float, float><<<pull_gx, 256, 0, stream>>>(x, cs_g, rowptr_g,
                                                        zA_x, N);                // h1
    accum_linear_k<float><<<nrx, 256, 0, stream>>>(zA_x, WlX, acc_x, N);
    spmm_g_k<float, float><<<pull_gx, 256, 0, stream>>>(zA_x, cs_g, rowptr_g,
                                                        zB_x, N);                // h2
    accum_linear_k<float><<<nrx, 256, 0, stream>>>(zB_x, WlX + 1024, acc_x, N);
    spmm_g_k<float, float><<<pull_gx, 256, 0, stream>>>(zB_x, cs_g, rowptr_g,
                                                        zA_x, N);                // h3
    spmm_g_k<float, float><<<pull_gx, 256, 0, stream>>>(zA_x, cs_g, rowptr_g,
                                                        zB_x, N);                // h4
    accum_linear_k<float><<<nrx, 256, 0, stream>>>(zB_x, WlX + 2048, acc_x, N);
    stats_k<<<512, 256, 0, stream>>>(acc_x, N, stats);

    // ---------- y side: spmm chain then one MFMA mega-GEMM ----------
    spmm_g_k<h16, h16><<<pull_gy, 256, 0, stream>>>(yh, cs_lg, rowptr_lg,
                                                    zh1, E);                     // h1
    spmm_g_k<h16, h16><<<pull_gy, 256, 0, stream>>>(zh1, cs_lg, rowptr_lg,
                                                    zh2, E);                     // h2
    spmm_g_k<h16, h16><<<pull_gy, 256, 0, stream>>>(zh2, cs_lg, rowptr_lg,
                                                    zh3, E);                     // h3
    spmm_g_k<h16, h16><<<pull_gy, 256, 0, stream>>>(zh3, cs_lg, rowptr_lg,
                                                    zh4, E);                     // h4 (into yh slot)
    mfma_y_k<<<mfma_gy, 256, 0, stream>>>(y, deg_lg, x, pm_pd,
                                          zh1, zh2, zh4, Why, btY, acc_y, E);
    stats_k<<<1024, 256, 0, stream>>>(acc_y, E, stats + 64);

    // ---------- BN fold + write ----------
    scalebias_k<<<1, 64, 0, stream>>>(stats, bn_x_sc, bn_x_bi, bn_y_sc, bn_y_bi,
                                      sb, N, E);
    finalize_k<<<(N * F + 255) / 256, 256, 0, stream>>>(acc_x, sb, out, N);
    finalize_k<<<(E * F + 255) / 256, 256, 0, stream>>>(acc_y, sb + 64,
                                                        out + (size_t)N * F, E);
}